// Round 4
// baseline (406.306 us; speedup 1.0000x reference)
//
#include <hip/hip_runtime.h>

typedef __bf16 bf16x8 __attribute__((ext_vector_type(8)));
typedef float f32x4 __attribute__((ext_vector_type(4)));

#define B_SZ 4
#define S_SZ 4096
#define D_SZ 1024
#define ELEMS_MAT ((size_t)B_SZ * S_SZ * D_SZ)   // 16,777,216

// ---- workspace layout (ushort elems), 174 MB total ----
#define OFF_Q  ((size_t)0)
#define OFF_K  (ELEMS_MAT)
#define OFF_VT (2 * ELEMS_MAT)
#define ZONE   (3 * ELEMS_MAT)
#define OFF_XB (ZONE)
#define OFF_V  (ZONE + ELEMS_MAT)
#define OFF_WT (ZONE + 2 * ELEMS_MAT)
#define OFF_S  (ZONE)                             // aliases xb+V+Wt (dead by then)
// S packed per batch: 16 row-blocks of 256 rows; block I at tri(I)*65536, row len (I+1)*256
#define S_BATCH ((size_t)8912896)                 // 136 tiles * 256*256

#define MFMA16(a, b, c) __builtin_amdgcn_mfma_f32_16x16x32_bf16((a), (b), (c), 0, 0, 0)

static __device__ __forceinline__ unsigned short f2bf(float f) {
  __bf16 h = (__bf16)f;
  return __builtin_bit_cast(unsigned short, h);
}

static __device__ __forceinline__ void async_lds16(const void* g, void* l) {
  __builtin_amdgcn_global_load_lds((__attribute__((address_space(1))) void*)g,
                                   (__attribute__((address_space(3))) void*)l, 16, 0, 0);
}

// ---------------- cast x (fp32 -> bf16) ----------------
__global__ void cast_x_kernel(const float* __restrict__ x, unsigned short* __restrict__ xb) {
  size_t i = ((size_t)blockIdx.x * 256 + threadIdx.x) * 8;
  f32x4 a = *(const f32x4*)(x + i);
  f32x4 b = *(const f32x4*)(x + i + 4);
  bf16x8 o;
  o[0] = (__bf16)a[0]; o[1] = (__bf16)a[1]; o[2] = (__bf16)a[2]; o[3] = (__bf16)a[3];
  o[4] = (__bf16)b[0]; o[5] = (__bf16)b[1]; o[6] = (__bf16)b[2]; o[7] = (__bf16)b[3];
  *(bf16x8*)(xb + i) = o;
}

// ---------------- transpose-cast weights: Wt[n][k] = bf16(W[k][n]); Wt = [3072][1024] ----------------
__global__ void cast_wt_kernel(const float* __restrict__ Wq, const float* __restrict__ Wk,
                               const float* __restrict__ Wv, unsigned short* __restrict__ Wt) {
  __shared__ float tl[64][65];
  const float* W = blockIdx.z == 0 ? Wq : (blockIdx.z == 1 ? Wk : Wv);
  unsigned short* out = Wt + (size_t)blockIdx.z * (size_t)D_SZ * (size_t)D_SZ;
  const int k0 = blockIdx.x * 64, n0 = blockIdx.y * 64;
  const int t = threadIdx.x;
  for (int i = t; i < 4096; i += 256) {
    int r = i >> 6, c = i & 63;
    tl[r][c] = W[(size_t)(k0 + r) * D_SZ + n0 + c];
  }
  __syncthreads();
  for (int i = t; i < 4096; i += 256) {
    int r = i >> 6, c = i & 63;
    out[(size_t)(n0 + r) * D_SZ + k0 + c] = f2bf(tl[c][r]);
  }
}

// ================= 256x256xBK64 8-wave GEMM template (T2+T4+T5) =================
// LDS tile: [rows][64 bf16] row-major (128B/row), byte swizzle: b ^= (row&7)<<4.
static __device__ __forceinline__ void stage_tile(const char* Asrc, size_t lda,
                                                  const char* Bsrc, size_t ldb,
                                                  unsigned short* ldsA, unsigned short* ldsB,
                                                  int tid) {
#pragma unroll
  for (int it = 0; it < 4; ++it) {
    int i = it * 512 + tid;
    int row = i >> 3;
    int scol = ((i & 7) ^ (row & 7)) << 4;
    async_lds16(Asrc + (size_t)row * lda + scol, (char*)ldsA + i * 16);
  }
#pragma unroll
  for (int it = 0; it < 4; ++it) {
    int i = it * 512 + tid;
    int row = i >> 3;
    int scol = ((i & 7) ^ (row & 7)) << 4;
    async_lds16(Bsrc + (size_t)row * ldb + scol, (char*)ldsB + i * 16);
  }
}

static __device__ __forceinline__ void compute_tile(const unsigned short* As,
                                                    const unsigned short* Bs,
                                                    int wm, int wn, int lr, int hi,
                                                    f32x4 acc[8][4]) {
  const char* Ab = (const char*)As;
  const char* Bb = (const char*)Bs;
#pragma unroll
  for (int q = 0; q < 4; ++q) {
    const int qm = q >> 1, qn = q & 1;
    bf16x8 af[4][2], bfr[2][2];
#pragma unroll
    for (int f = 0; f < 4; ++f) {
      const int r = wm * 128 + (qm * 4 + f) * 16 + lr;
#pragma unroll
      for (int kk = 0; kk < 2; ++kk)
        af[f][kk] = *(const bf16x8*)(Ab + r * 128 + ((kk * 64 + hi * 16) ^ ((r & 7) << 4)));
    }
#pragma unroll
    for (int f = 0; f < 2; ++f) {
      const int r = wn * 64 + (qn * 2 + f) * 16 + lr;
#pragma unroll
      for (int kk = 0; kk < 2; ++kk)
        bfr[f][kk] = *(const bf16x8*)(Bb + r * 128 + ((kk * 64 + hi * 16) ^ ((r & 7) << 4)));
    }
    __builtin_amdgcn_s_setprio(1);
#pragma unroll
    for (int kk = 0; kk < 2; ++kk)
#pragma unroll
      for (int f = 0; f < 4; ++f)
#pragma unroll
        for (int g = 0; g < 2; ++g)
          acc[qm * 4 + f][qn * 2 + g] = MFMA16(af[f][kk], bfr[g][kk], acc[qm * 4 + f][qn * 2 + g]);
    __builtin_amdgcn_s_setprio(0);
  }
}

static __device__ __forceinline__ void gemm_mainloop(const char* A, size_t lda,
                                                     const char* B, size_t ldb, int NT,
                                                     unsigned short sm[2][2][16384],
                                                     int tid, f32x4 acc[8][4]) {
  const int lane = tid & 63, w = tid >> 6;
  const int wm = w >> 2, wn = w & 3, lr = lane & 15, hi = lane >> 4;
  stage_tile(A, lda, B, ldb, sm[0][0], sm[0][1], tid);
  for (int t = 0; t < NT - 1; ++t) {
    const int cur = t & 1;
    stage_tile(A + (size_t)(t + 1) * 128, lda, B + (size_t)(t + 1) * 128, ldb,
               sm[cur ^ 1][0], sm[cur ^ 1][1], tid);
    asm volatile("s_waitcnt vmcnt(8)" ::: "memory");
    __builtin_amdgcn_s_barrier();
    compute_tile(sm[cur][0], sm[cur][1], wm, wn, lr, hi, acc);
    __builtin_amdgcn_s_barrier();
  }
  asm volatile("s_waitcnt vmcnt(0)" ::: "memory");
  __builtin_amdgcn_s_barrier();
  compute_tile(sm[(NT - 1) & 1][0], sm[(NT - 1) & 1][1], wm, wn, lr, hi, acc);
}

#define GEMM_PRE()                                    \
  __shared__ unsigned short sm[2][2][16384];          \
  const int tid = threadIdx.x;                        \
  f32x4 acc[8][4];                                    \
  {                                                   \
    const f32x4 z4 = {0.f, 0.f, 0.f, 0.f};            \
    _Pragma("unroll") for (int f = 0; f < 8; ++f)     \
      _Pragma("unroll") for (int g = 0; g < 4; ++g)   \
        acc[f][g] = z4;                               \
  }

#define EPI_IDX()                                     \
  const int lane = tid & 63, w = tid >> 6;            \
  const int wm = w >> 2, wn = w & 3;                  \
  const int lr = lane & 15, hi = lane >> 4;

// ---------------- QKV: [16384,1024] x [1024,3072] ----------------
__global__ __launch_bounds__(512, 2) void gemm_qkv256(const unsigned short* __restrict__ xb,
                                                      const unsigned short* __restrict__ Wt,
                                                      unsigned short* __restrict__ Q,
                                                      unsigned short* __restrict__ K,
                                                      unsigned short* __restrict__ V) {
  GEMM_PRE();
  const int bid = blockIdx.x;
  const int sw = (bid & 7) * 96 + (bid >> 3);   // XCD swizzle (768 = 8*96)
  const int mt = sw % 64, nt = sw / 64;         // nt in [0,12)
  const char* A = (const char*)xb + (size_t)mt * 256 * 2048;
  const char* Bp = (const char*)Wt + (size_t)nt * 256 * 2048;
  gemm_mainloop(A, 2048, Bp, 2048, 16, sm, tid, acc);
  EPI_IDX();
  unsigned short* Out = (nt >> 2) == 0 ? Q : ((nt >> 2) == 1 ? K : V);
  const int nb = (nt & 3) * 256;
#pragma unroll
  for (int f = 0; f < 8; ++f)
#pragma unroll
    for (int g = 0; g < 4; ++g)
#pragma unroll
      for (int j = 0; j < 4; ++j) {
        const int m = mt * 256 + wm * 128 + f * 16 + hi * 4 + j;
        const int n = nb + wn * 64 + g * 16 + lr;
        Out[(size_t)m * D_SZ + n] = f2bf(acc[f][g][j]);
      }
}

// ================= BN=128 variant: BM=256 x BN=128 x BK=64, 8 waves 2Mx4N =================
// LDS: A [256][64] (32 KiB), B [128][64] (16 KiB), double-buffered = 96 KiB.
static __device__ __forceinline__ void stage_a256(const char* src, size_t ld, char* lds, int tid) {
#pragma unroll
  for (int it = 0; it < 4; ++it) {
    int i = it * 512 + tid;
    int row = i >> 3;
    int scol = ((i & 7) ^ (row & 7)) << 4;
    async_lds16(src + (size_t)row * ld + scol, lds + i * 16);
  }
}
static __device__ __forceinline__ void stage_b128(const char* src, size_t ld, char* lds, int tid) {
#pragma unroll
  for (int it = 0; it < 2; ++it) {
    int i = it * 512 + tid;
    int row = i >> 3;
    int scol = ((i & 7) ^ (row & 7)) << 4;
    async_lds16(src + (size_t)row * ld + scol, lds + i * 16);
  }
}

static __device__ __forceinline__ void compute_tile128(const unsigned short* As,
                                                       const unsigned short* Bs,
                                                       int wm, int wn, int lr, int hi,
                                                       f32x4 acc[8][2]) {
  const char* Ab = (const char*)As;
  const char* Bb = (const char*)Bs;
  bf16x8 bfr[2][2];
#pragma unroll
  for (int g = 0; g < 2; ++g) {
    const int r = wn * 32 + g * 16 + lr;
#pragma unroll
    for (int kk = 0; kk < 2; ++kk)
      bfr[g][kk] = *(const bf16x8*)(Bb + r * 128 + ((kk * 64 + hi * 16) ^ ((r & 7) << 4)));
  }
#pragma unroll
  for (int p = 0; p < 4; ++p) {
    bf16x8 af[2][2];
#pragma unroll
    for (int f = 0; f < 2; ++f) {
      const int r = wm * 128 + (p * 2 + f) * 16 + lr;
#pragma unroll
      for (int kk = 0; kk < 2; ++kk)
        af[f][kk] = *(const bf16x8*)(Ab + r * 128 + ((kk * 64 + hi * 16) ^ ((r & 7) << 4)));
    }
    __builtin_amdgcn_s_setprio(1);
#pragma unroll
    for (int kk = 0; kk < 2; ++kk)
#pragma unroll
      for (int f = 0; f < 2; ++f)
#pragma unroll
        for (int g = 0; g < 2; ++g)
          acc[p * 2 + f][g] = MFMA16(af[f][kk], bfr[g][kk], acc[p * 2 + f][g]);
    __builtin_amdgcn_s_setprio(0);
  }
}

static __device__ __forceinline__ void mainloop128(const char* A, size_t lda,
                                                   const char* B, size_t ldb, int NT,
                                                   unsigned short (*smA)[16384],
                                                   unsigned short (*smB)[8192],
                                                   int tid, f32x4 acc[8][2]) {
  const int lane = tid & 63, w = tid >> 6;
  const int wm = w >> 2, wn = w & 3, lr = lane & 15, hi = lane >> 4;
  stage_a256(A, lda, (char*)smA[0], tid);
  stage_b128(B, ldb, (char*)smB[0], tid);
  for (int t = 0; t < NT - 1; ++t) {
    const int cur = t & 1;
    stage_a256(A + (size_t)(t + 1) * 128, lda, (char*)smA[cur ^ 1], tid);
    stage_b128(B + (size_t)(t + 1) * 128, ldb, (char*)smB[cur ^ 1], tid);
    asm volatile("s_waitcnt vmcnt(6)" ::: "memory");
    __builtin_amdgcn_s_barrier();
    compute_tile128(smA[cur], smB[cur], wm, wn, lr, hi, acc);
    __builtin_amdgcn_s_barrier();
  }
  asm volatile("s_waitcnt vmcnt(0)" ::: "memory");
  __builtin_amdgcn_s_barrier();
  compute_tile128(smA[(NT - 1) & 1], smB[(NT - 1) & 1], wm, wn, lr, hi, acc);
}

// ---------------- transpose V: Vt[b][d][s] = V[b][s][d] ----------------
__global__ void transpose_v_kernel(const unsigned short* __restrict__ V,
                                   unsigned short* __restrict__ Vt) {
  __shared__ unsigned short tl[64][65];
  const int s0 = blockIdx.x * 64, d0 = blockIdx.y * 64, b = blockIdx.z;
  const int t = threadIdx.x;
  const unsigned short* Vb = V + (size_t)b * S_SZ * D_SZ;
  unsigned short* Vo = Vt + (size_t)b * D_SZ * S_SZ;
  for (int i = t; i < 4096; i += 256) {
    int r = i >> 6, c = i & 63;
    tl[r][c] = Vb[(size_t)(s0 + r) * D_SZ + d0 + c];
  }
  __syncthreads();
  for (int i = t; i < 4096; i += 256) {
    int r = i >> 6, c = i & 63;
    Vo[(size_t)(d0 + r) * S_SZ + s0 + c] = tl[c][r];
  }
}

// ---------------- S = (Q K^T)/32: 256-row x 128-col tiles, packed ----------------
// Per batch: 272 tiles; flat r = I*(I+1) + Jh, Jh in [0, 2I+2).
__global__ __launch_bounds__(512, 2) void s_gemm_bn128(const unsigned short* __restrict__ Q,
                                                       const unsigned short* __restrict__ K,
                                                       unsigned short* __restrict__ Sp) {
  __shared__ unsigned short smA[2][16384];
  __shared__ unsigned short smB[2][8192];
  const int tid = threadIdx.x;
  f32x4 acc[8][2];
  {
    const f32x4 z4 = {0.f, 0.f, 0.f, 0.f};
#pragma unroll
    for (int f = 0; f < 8; ++f)
#pragma unroll
      for (int g = 0; g < 2; ++g) acc[f][g] = z4;
  }
  const int bid = blockIdx.x;
  const int sw = (bid & 7) * 136 + (bid >> 3);  // 1088 = 8*136, bijective
  const int b = sw / 272;
  const int r = sw % 272;
  int I = (int)((sqrtf(4.0f * r + 1.0f) - 1.0f) * 0.5f);
  while ((I + 1) * (I + 2) <= r) ++I;
  while (I * (I + 1) > r) --I;
  const int Jh = r - I * (I + 1);

  const char* A = (const char*)Q + ((size_t)b * S_SZ + (size_t)I * 256) * 2048;
  const char* Bp = (const char*)K + ((size_t)b * S_SZ + (size_t)Jh * 128) * 2048;
  mainloop128(A, 2048, Bp, 2048, 16, smA, smB, tid, acc);
  EPI_IDX();
  const int L = (I + 1) * 256;
  unsigned short* So = Sp + (size_t)b * S_BATCH + (size_t)(I * (I + 1) / 2) * 65536;
#pragma unroll
  for (int f = 0; f < 8; ++f)
#pragma unroll
    for (int g = 0; g < 2; ++g)
#pragma unroll
      for (int j = 0; j < 4; ++j) {
        const int m = wm * 128 + f * 16 + hi * 4 + j;        // local row
        const int n = Jh * 128 + wn * 32 + g * 16 + lr;      // global col
        float val = acc[f][g][j] * 0.03125f;                 // 1/sqrt(1024)
        if (n > I * 256 + m) val = -1e30f;                   // causal mask
        So[(size_t)m * L + n] = f2bf(val);
      }
}

// ---------------- row softmax in place on packed S (wave per row) ----------------
__global__ __launch_bounds__(256) void softmax_kernel(unsigned short* __restrict__ Sp) {
  const int w = threadIdx.x >> 6, lane = threadIdx.x & 63;
  const int rowflat = blockIdx.x * 4 + w;
  const int rr = 16383 - rowflat;              // heavy rows first
  const int b = rr >> 12, q = rr & 4095;
  const int I = q >> 8;
  const int L = (I + 1) << 8;
  unsigned short* base = Sp + (size_t)b * S_BATCH + (size_t)(I * (I + 1) / 2) * 65536 +
                         (size_t)(q & 255) * L;
  const int niter = (L + 511) >> 9;            // chunks of 512 elems (64 lanes x 8)
  const __bf16 NEG = (__bf16)(-1e30f);
  bf16x8 v[8];
#pragma unroll
  for (int jt = 0; jt < 8; ++jt) {
    if (jt < niter) {
      const int off = jt * 512 + lane * 8;
      if (off < L) v[jt] = *(const bf16x8*)(base + off);
      else { bf16x8 fz; fz[0]=NEG;fz[1]=NEG;fz[2]=NEG;fz[3]=NEG;fz[4]=NEG;fz[5]=NEG;fz[6]=NEG;fz[7]=NEG; v[jt] = fz; }
    }
  }
  float m = -1e30f;
#pragma unroll
  for (int jt = 0; jt < 8; ++jt)
    if (jt < niter)
#pragma unroll
      for (int e = 0; e < 8; ++e) m = fmaxf(m, (float)v[jt][e]);
  m = fmaxf(m, __shfl_xor(m, 1));  m = fmaxf(m, __shfl_xor(m, 2));
  m = fmaxf(m, __shfl_xor(m, 4));  m = fmaxf(m, __shfl_xor(m, 8));
  m = fmaxf(m, __shfl_xor(m, 16)); m = fmaxf(m, __shfl_xor(m, 32));
  float l = 0.f;
#pragma unroll
  for (int jt = 0; jt < 8; ++jt)
    if (jt < niter)
#pragma unroll
      for (int e = 0; e < 8; ++e) l += __expf((float)v[jt][e] - m);
  l += __shfl_xor(l, 1);  l += __shfl_xor(l, 2);  l += __shfl_xor(l, 4);
  l += __shfl_xor(l, 8);  l += __shfl_xor(l, 16); l += __shfl_xor(l, 32);
  const float rl = 1.0f / l;
#pragma unroll
  for (int jt = 0; jt < 8; ++jt) {
    if (jt < niter) {
      const int off = jt * 512 + lane * 8;
      if (off < L) {
        bf16x8 p;
#pragma unroll
        for (int e = 0; e < 8; ++e) p[e] = (__bf16)(__expf((float)v[jt][e] - m) * rl);
        *(bf16x8*)(base + off) = p;
      }
    }
  }
}

// ---------------- O = P V, paired row-blocks for perfect balance ----------------
// 256 blocks; block handles I = p and I = 15-p -> 68 K-steps each, uniform.
__global__ __launch_bounds__(512, 2) void pv_bal(const unsigned short* __restrict__ Sp,
                                                 const unsigned short* __restrict__ Vt,
                                                 float* __restrict__ out) {
  __shared__ unsigned short smA[2][16384];
  __shared__ unsigned short smB[2][8192];
  const int tid = threadIdx.x;
  const int bid = blockIdx.x;
  const int sw = (bid & 7) * 32 + (bid >> 3);   // 256 = 8*32, bijective
  const int p = sw >> 5, b = (sw >> 3) & 3, nt = sw & 7;
  EPI_IDX();
  f32x4 acc[8][2];
#pragma unroll
  for (int half = 0; half < 2; ++half) {
    const int I = half ? (15 - p) : p;
    {
      const f32x4 z4 = {0.f, 0.f, 0.f, 0.f};
#pragma unroll
      for (int f = 0; f < 8; ++f)
#pragma unroll
        for (int g = 0; g < 2; ++g) acc[f][g] = z4;
    }
    const char* A = (const char*)(Sp + (size_t)b * S_BATCH + (size_t)(I * (I + 1) / 2) * 65536);
    const size_t lda = (size_t)(I + 1) * 512;   // bytes
    const char* Bp = (const char*)Vt + ((size_t)b * D_SZ + (size_t)nt * 128) * (S_SZ * 2);
    mainloop128(A, lda, Bp, S_SZ * 2, (I + 1) * 4, smA, smB, tid, acc);
#pragma unroll
    for (int f = 0; f < 8; ++f)
#pragma unroll
      for (int g = 0; g < 2; ++g)
#pragma unroll
        for (int j = 0; j < 4; ++j) {
          const int m = wm * 128 + f * 16 + hi * 4 + j;
          const int n = nt * 128 + wn * 32 + g * 16 + lr;
          out[((size_t)b * S_SZ + (size_t)I * 256 + m) * D_SZ + n] = acc[f][g][j];
        }
    __syncthreads();
  }
}

extern "C" void kernel_launch(void* const* d_in, const int* in_sizes, int n_in,
                              void* d_out, int out_size, void* d_ws, size_t ws_size,
                              hipStream_t stream) {
  (void)in_sizes; (void)n_in; (void)out_size; (void)ws_size;
  const float* x  = (const float*)d_in[0];
  const float* Wq = (const float*)d_in[1];
  const float* Wk = (const float*)d_in[2];
  const float* Wv = (const float*)d_in[3];
  float* out = (float*)d_out;
  unsigned short* ws = (unsigned short*)d_ws;

  cast_x_kernel<<<8192, 256, 0, stream>>>(x, ws + OFF_XB);
  cast_wt_kernel<<<dim3(16, 16, 3), 256, 0, stream>>>(Wq, Wk, Wv, ws + OFF_WT);
  gemm_qkv256<<<768, 512, 0, stream>>>(ws + OFF_XB, ws + OFF_WT,
                                       ws + OFF_Q, ws + OFF_K, ws + OFF_V);
  transpose_v_kernel<<<dim3(64, 16, 4), 256, 0, stream>>>(ws + OFF_V, ws + OFF_VT);
  s_gemm_bn128<<<1088, 512, 0, stream>>>(ws + OFF_Q, ws + OFF_K, ws + OFF_S);
  softmax_kernel<<<4096, 256, 0, stream>>>(ws + OFF_S);
  pv_bal<<<256, 512, 0, stream>>>(ws + OFF_S, ws + OFF_VT, out);
}

// Round 5
// 370.411 us; speedup vs baseline: 1.0969x; 1.0969x over previous
//
#include <hip/hip_runtime.h>

typedef __bf16 bf16x8 __attribute__((ext_vector_type(8)));
typedef float f32x4 __attribute__((ext_vector_type(4)));

#define B_SZ 4
#define S_SZ 4096
#define D_SZ 1024
#define ELEMS_MAT ((size_t)B_SZ * S_SZ * D_SZ)   // 16,777,216

// ---- workspace layout (ushort elems), 174 MB total ----
#define OFF_Q  ((size_t)0)
#define OFF_K  (ELEMS_MAT)
#define OFF_VT (2 * ELEMS_MAT)
#define ZONE   (3 * ELEMS_MAT)
#define OFF_XB (ZONE)
#define OFF_V  (ZONE + ELEMS_MAT)
#define OFF_WT (ZONE + 2 * ELEMS_MAT)
#define OFF_S  (ZONE)                             // aliases xb+V+Wt (dead by then)
// S packed per batch: 16 row-blocks of 256 rows; block I at tri(I)*65536, row len (I+1)*256
#define S_BATCH ((size_t)8912896)                 // 136 tiles * 256*256

#define MFMA16(a, b, c) __builtin_amdgcn_mfma_f32_16x16x32_bf16((a), (b), (c), 0, 0, 0)

static __device__ __forceinline__ unsigned short f2bf(float f) {
  __bf16 h = (__bf16)f;
  return __builtin_bit_cast(unsigned short, h);
}

static __device__ __forceinline__ void async_lds16(const void* g, void* l) {
  __builtin_amdgcn_global_load_lds((__attribute__((address_space(1))) void*)g,
                                   (__attribute__((address_space(3))) void*)l, 16, 0, 0);
}

// ---------------- cast x (fp32 -> bf16) ----------------
__global__ void cast_x_kernel(const float* __restrict__ x, unsigned short* __restrict__ xb) {
  size_t i = ((size_t)blockIdx.x * 256 + threadIdx.x) * 8;
  f32x4 a = *(const f32x4*)(x + i);
  f32x4 b = *(const f32x4*)(x + i + 4);
  bf16x8 o;
  o[0] = (__bf16)a[0]; o[1] = (__bf16)a[1]; o[2] = (__bf16)a[2]; o[3] = (__bf16)a[3];
  o[4] = (__bf16)b[0]; o[5] = (__bf16)b[1]; o[6] = (__bf16)b[2]; o[7] = (__bf16)b[3];
  *(bf16x8*)(xb + i) = o;
}

// ---------------- transpose-cast weights: Wt[n][k] = bf16(W[k][n]); Wt = [3072][1024] ----------------
__global__ void cast_wt_kernel(const float* __restrict__ Wq, const float* __restrict__ Wk,
                               const float* __restrict__ Wv, unsigned short* __restrict__ Wt) {
  __shared__ float tl[64][65];
  const float* W = blockIdx.z == 0 ? Wq : (blockIdx.z == 1 ? Wk : Wv);
  unsigned short* out = Wt + (size_t)blockIdx.z * (size_t)D_SZ * (size_t)D_SZ;
  const int k0 = blockIdx.x * 64, n0 = blockIdx.y * 64;
  const int t = threadIdx.x;
  for (int i = t; i < 4096; i += 256) {
    int r = i >> 6, c = i & 63;
    tl[r][c] = W[(size_t)(k0 + r) * D_SZ + n0 + c];
  }
  __syncthreads();
  for (int i = t; i < 4096; i += 256) {
    int r = i >> 6, c = i & 63;
    out[(size_t)(n0 + r) * D_SZ + k0 + c] = f2bf(tl[c][r]);
  }
}

// ================= 256x256xBK64 8-wave GEMM template (T2+T4+T5) =================
// LDS tile: [rows][64 bf16] row-major (128B/row), byte swizzle: b ^= (row&7)<<4.
static __device__ __forceinline__ void stage_tile(const char* Asrc, size_t lda,
                                                  const char* Bsrc, size_t ldb,
                                                  unsigned short* ldsA, unsigned short* ldsB,
                                                  int tid) {
#pragma unroll
  for (int it = 0; it < 4; ++it) {
    int i = it * 512 + tid;
    int row = i >> 3;
    int scol = ((i & 7) ^ (row & 7)) << 4;
    async_lds16(Asrc + (size_t)row * lda + scol, (char*)ldsA + i * 16);
  }
#pragma unroll
  for (int it = 0; it < 4; ++it) {
    int i = it * 512 + tid;
    int row = i >> 3;
    int scol = ((i & 7) ^ (row & 7)) << 4;
    async_lds16(Bsrc + (size_t)row * ldb + scol, (char*)ldsB + i * 16);
  }
}

// Fragment-minimal compute: every af/bfr read exactly once per wave (24 b128/wave/tile).
static __device__ __forceinline__ void compute_tile(const unsigned short* As,
                                                    const unsigned short* Bs,
                                                    int wm, int wn, int lr, int hi,
                                                    f32x4 acc[8][4]) {
  const char* Ab = (const char*)As;
  const char* Bb = (const char*)Bs;
  bf16x8 bfr[4][2];
#pragma unroll
  for (int g = 0; g < 4; ++g) {
    const int r = wn * 64 + g * 16 + lr;
#pragma unroll
    for (int kk = 0; kk < 2; ++kk)
      bfr[g][kk] = *(const bf16x8*)(Bb + r * 128 + ((kk * 64 + hi * 16) ^ ((r & 7) << 4)));
  }
#pragma unroll
  for (int qm = 0; qm < 2; ++qm) {
    bf16x8 af[4][2];
#pragma unroll
    for (int f = 0; f < 4; ++f) {
      const int r = wm * 128 + (qm * 4 + f) * 16 + lr;
#pragma unroll
      for (int kk = 0; kk < 2; ++kk)
        af[f][kk] = *(const bf16x8*)(Ab + r * 128 + ((kk * 64 + hi * 16) ^ ((r & 7) << 4)));
    }
    __builtin_amdgcn_s_setprio(1);
#pragma unroll
    for (int kk = 0; kk < 2; ++kk)
#pragma unroll
      for (int f = 0; f < 4; ++f)
#pragma unroll
        for (int g = 0; g < 4; ++g)
          acc[qm * 4 + f][g] = MFMA16(af[f][kk], bfr[g][kk], acc[qm * 4 + f][g]);
    __builtin_amdgcn_s_setprio(0);
  }
}

static __device__ __forceinline__ void gemm_mainloop(const char* A, size_t lda,
                                                     const char* B, size_t ldb, int NT,
                                                     unsigned short sm[2][2][16384],
                                                     int tid, f32x4 acc[8][4]) {
  const int lane = tid & 63, w = tid >> 6;
  const int wm = w >> 2, wn = w & 3, lr = lane & 15, hi = lane >> 4;
  stage_tile(A, lda, B, ldb, sm[0][0], sm[0][1], tid);
  for (int t = 0; t < NT - 1; ++t) {
    const int cur = t & 1;
    stage_tile(A + (size_t)(t + 1) * 128, lda, B + (size_t)(t + 1) * 128, ldb,
               sm[cur ^ 1][0], sm[cur ^ 1][1], tid);
    asm volatile("s_waitcnt vmcnt(8)" ::: "memory");
    __builtin_amdgcn_s_barrier();
    compute_tile(sm[cur][0], sm[cur][1], wm, wn, lr, hi, acc);
    __builtin_amdgcn_s_barrier();
  }
  asm volatile("s_waitcnt vmcnt(0)" ::: "memory");
  __builtin_amdgcn_s_barrier();
  compute_tile(sm[(NT - 1) & 1][0], sm[(NT - 1) & 1][1], wm, wn, lr, hi, acc);
}

#define GEMM_PRE()                                    \
  __shared__ unsigned short sm[2][2][16384];          \
  const int tid = threadIdx.x;                        \
  f32x4 acc[8][4];                                    \
  {                                                   \
    const f32x4 z4 = {0.f, 0.f, 0.f, 0.f};            \
    _Pragma("unroll") for (int f = 0; f < 8; ++f)     \
      _Pragma("unroll") for (int g = 0; g < 4; ++g)   \
        acc[f][g] = z4;                               \
  }

#define EPI_IDX()                                     \
  const int lane = tid & 63, w = tid >> 6;            \
  const int wm = w >> 2, wn = w & 3;                  \
  const int lr = lane & 15, hi = lane >> 4;

// ---------------- QKV: [16384,1024] x [1024,3072] ----------------
__global__ __launch_bounds__(512, 2) void gemm_qkv256(const unsigned short* __restrict__ xb,
                                                      const unsigned short* __restrict__ Wt,
                                                      unsigned short* __restrict__ Q,
                                                      unsigned short* __restrict__ K,
                                                      unsigned short* __restrict__ V) {
  GEMM_PRE();
  const int bid = blockIdx.x;
  const int sw = (bid & 7) * 96 + (bid >> 3);   // XCD swizzle (768 = 8*96)
  const int mt = sw % 64, nt = sw / 64;         // nt in [0,12)
  const char* A = (const char*)xb + (size_t)mt * 256 * 2048;
  const char* Bp = (const char*)Wt + (size_t)nt * 256 * 2048;
  gemm_mainloop(A, 2048, Bp, 2048, 16, sm, tid, acc);
  EPI_IDX();
  unsigned short* Out = (nt >> 2) == 0 ? Q : ((nt >> 2) == 1 ? K : V);
  const int nb = (nt & 3) * 256;
#pragma unroll
  for (int f = 0; f < 8; ++f)
#pragma unroll
    for (int g = 0; g < 4; ++g)
#pragma unroll
      for (int j = 0; j < 4; ++j) {
        const int m = mt * 256 + wm * 128 + f * 16 + hi * 4 + j;
        const int n = nb + wn * 64 + g * 16 + lr;
        Out[(size_t)m * D_SZ + n] = f2bf(acc[f][g][j]);
      }
}

// ---------------- transpose V: Vt[b][d][s] = V[b][s][d] ----------------
__global__ void transpose_v_kernel(const unsigned short* __restrict__ V,
                                   unsigned short* __restrict__ Vt) {
  __shared__ unsigned short tl[64][65];
  const int s0 = blockIdx.x * 64, d0 = blockIdx.y * 64, b = blockIdx.z;
  const int t = threadIdx.x;
  const unsigned short* Vb = V + (size_t)b * S_SZ * D_SZ;
  unsigned short* Vo = Vt + (size_t)b * D_SZ * S_SZ;
  for (int i = t; i < 4096; i += 256) {
    int r = i >> 6, c = i & 63;
    tl[r][c] = Vb[(size_t)(s0 + r) * D_SZ + d0 + c];
  }
  __syncthreads();
  for (int i = t; i < 4096; i += 256) {
    int r = i >> 6, c = i & 63;
    Vo[(size_t)(d0 + r) * S_SZ + s0 + c] = tl[c][r];
  }
}

// ---------------- S = (Q K^T)/32, 256x256 lower-tri tiles, packed ----------------
__global__ __launch_bounds__(512, 2) void s_gemm256(const unsigned short* __restrict__ Q,
                                                    const unsigned short* __restrict__ K,
                                                    unsigned short* __restrict__ Sp) {
  GEMM_PRE();
  const int bid = blockIdx.x;
  const int sw = (bid & 7) * 68 + (bid >> 3);   // XCD swizzle (544 = 8*68)
  const int b = sw / 136;
  const int tile = sw % 136;
  int I = (int)((sqrtf(8.0f * tile + 1.0f) - 1.0f) * 0.5f);
  while ((I + 1) * (I + 2) / 2 <= tile) ++I;
  while (I * (I + 1) / 2 > tile) --I;
  const int J = tile - I * (I + 1) / 2;
  const char* A = (const char*)Q + ((size_t)b * S_SZ + (size_t)I * 256) * 2048;
  const char* Bp = (const char*)K + ((size_t)b * S_SZ + (size_t)J * 256) * 2048;
  gemm_mainloop(A, 2048, Bp, 2048, 16, sm, tid, acc);
  EPI_IDX();
  const int L = (I + 1) * 256;
  unsigned short* So = Sp + (size_t)b * S_BATCH + (size_t)(I * (I + 1) / 2) * 65536;
#pragma unroll
  for (int f = 0; f < 8; ++f)
#pragma unroll
    for (int g = 0; g < 4; ++g)
#pragma unroll
      for (int j = 0; j < 4; ++j) {
        const int m = wm * 128 + f * 16 + hi * 4 + j;        // local row
        const int n = J * 256 + wn * 64 + g * 16 + lr;       // global col
        float val = acc[f][g][j] * 0.03125f;                 // 1/sqrt(1024)
        if (n > I * 256 + m) val = -1e30f;                   // causal mask
        So[(size_t)m * L + n] = f2bf(val);
      }
}

// ---------------- row softmax in place on packed S (wave per row) ----------------
__global__ __launch_bounds__(256) void softmax_kernel(unsigned short* __restrict__ Sp) {
  const int w = threadIdx.x >> 6, lane = threadIdx.x & 63;
  const int rowflat = blockIdx.x * 4 + w;
  const int rr = 16383 - rowflat;              // heavy rows first
  const int b = rr >> 12, q = rr & 4095;
  const int I = q >> 8;
  const int L = (I + 1) << 8;
  unsigned short* base = Sp + (size_t)b * S_BATCH + (size_t)(I * (I + 1) / 2) * 65536 +
                         (size_t)(q & 255) * L;
  const int niter = (L + 511) >> 9;            // chunks of 512 elems (64 lanes x 8)
  const __bf16 NEG = (__bf16)(-1e30f);
  bf16x8 v[8];
#pragma unroll
  for (int jt = 0; jt < 8; ++jt) {
    if (jt < niter) {
      const int off = jt * 512 + lane * 8;
      if (off < L) v[jt] = *(const bf16x8*)(base + off);
      else { bf16x8 fz; fz[0]=NEG;fz[1]=NEG;fz[2]=NEG;fz[3]=NEG;fz[4]=NEG;fz[5]=NEG;fz[6]=NEG;fz[7]=NEG; v[jt] = fz; }
    }
  }
  float m = -1e30f;
#pragma unroll
  for (int jt = 0; jt < 8; ++jt)
    if (jt < niter)
#pragma unroll
      for (int e = 0; e < 8; ++e) m = fmaxf(m, (float)v[jt][e]);
  m = fmaxf(m, __shfl_xor(m, 1));  m = fmaxf(m, __shfl_xor(m, 2));
  m = fmaxf(m, __shfl_xor(m, 4));  m = fmaxf(m, __shfl_xor(m, 8));
  m = fmaxf(m, __shfl_xor(m, 16)); m = fmaxf(m, __shfl_xor(m, 32));
  float l = 0.f;
#pragma unroll
  for (int jt = 0; jt < 8; ++jt)
    if (jt < niter)
#pragma unroll
      for (int e = 0; e < 8; ++e) l += __expf((float)v[jt][e] - m);
  l += __shfl_xor(l, 1);  l += __shfl_xor(l, 2);  l += __shfl_xor(l, 4);
  l += __shfl_xor(l, 8);  l += __shfl_xor(l, 16); l += __shfl_xor(l, 32);
  const float rl = 1.0f / l;
#pragma unroll
  for (int jt = 0; jt < 8; ++jt) {
    if (jt < niter) {
      const int off = jt * 512 + lane * 8;
      if (off < L) {
        bf16x8 p;
#pragma unroll
        for (int e = 0; e < 8; ++e) p[e] = (__bf16)(__expf((float)v[jt][e] - m) * rl);
        *(bf16x8*)(base + off) = p;
      }
    }
  }
}

// ================= BN=128 PV variant: BM=256 x BN=128 x BK=64, 8 waves 4Mx2N =================
// LDS: A [256][64] (32 KiB), B [128][64] (16 KiB), double-buffered = 96 KiB.
static __device__ __forceinline__ void stage_a256(const char* src, size_t ld, char* lds, int tid) {
#pragma unroll
  for (int it = 0; it < 4; ++it) {
    int i = it * 512 + tid;
    int row = i >> 3;
    int scol = ((i & 7) ^ (row & 7)) << 4;
    async_lds16(src + (size_t)row * ld + scol, lds + i * 16);
  }
}
static __device__ __forceinline__ void stage_b128(const char* src, size_t ld, char* lds, int tid) {
#pragma unroll
  for (int it = 0; it < 2; ++it) {
    int i = it * 512 + tid;
    int row = i >> 3;
    int scol = ((i & 7) ^ (row & 7)) << 4;
    async_lds16(src + (size_t)row * ld + scol, lds + i * 16);
  }
}

// wave-tile 64x64 (4M x 2N waves): 16 b128 frag reads/wave/tile, all hoisted.
static __device__ __forceinline__ void compute_tile128(const unsigned short* As,
                                                       const unsigned short* Bs,
                                                       int wm, int wn, int lr, int hi,
                                                       f32x4 acc[4][4]) {
  const char* Ab = (const char*)As;
  const char* Bb = (const char*)Bs;
  bf16x8 bfr[4][2];
#pragma unroll
  for (int g = 0; g < 4; ++g) {
    const int r = wn * 64 + g * 16 + lr;
#pragma unroll
    for (int kk = 0; kk < 2; ++kk)
      bfr[g][kk] = *(const bf16x8*)(Bb + r * 128 + ((kk * 64 + hi * 16) ^ ((r & 7) << 4)));
  }
  bf16x8 af[4][2];
#pragma unroll
  for (int f = 0; f < 4; ++f) {
    const int r = wm * 64 + f * 16 + lr;
#pragma unroll
    for (int kk = 0; kk < 2; ++kk)
      af[f][kk] = *(const bf16x8*)(Ab + r * 128 + ((kk * 64 + hi * 16) ^ ((r & 7) << 4)));
  }
  __builtin_amdgcn_s_setprio(1);
#pragma unroll
  for (int kk = 0; kk < 2; ++kk)
#pragma unroll
    for (int f = 0; f < 4; ++f)
#pragma unroll
      for (int g = 0; g < 4; ++g)
        acc[f][g] = MFMA16(af[f][kk], bfr[g][kk], acc[f][g]);
  __builtin_amdgcn_s_setprio(0);
}

static __device__ __forceinline__ void mainloop128(const char* A, size_t lda,
                                                   const char* B, size_t ldb, int NT,
                                                   unsigned short (*smA)[16384],
                                                   unsigned short (*smB)[8192],
                                                   int tid, f32x4 acc[4][4]) {
  const int lane = tid & 63, w = tid >> 6;
  const int wm = w >> 1, wn = w & 1, lr = lane & 15, hi = lane >> 4;
  stage_a256(A, lda, (char*)smA[0], tid);
  stage_b128(B, ldb, (char*)smB[0], tid);
  for (int t = 0; t < NT - 1; ++t) {
    const int cur = t & 1;
    stage_a256(A + (size_t)(t + 1) * 128, lda, (char*)smA[cur ^ 1], tid);
    stage_b128(B + (size_t)(t + 1) * 128, ldb, (char*)smB[cur ^ 1], tid);
    asm volatile("s_waitcnt vmcnt(6)" ::: "memory");
    __builtin_amdgcn_s_barrier();
    compute_tile128(smA[cur], smB[cur], wm, wn, lr, hi, acc);
    __builtin_amdgcn_s_barrier();
  }
  asm volatile("s_waitcnt vmcnt(0)" ::: "memory");
  __builtin_amdgcn_s_barrier();
  compute_tile128(smA[(NT - 1) & 1], smB[(NT - 1) & 1], wm, wn, lr, hi, acc);
}

// ---------------- O = P V, paired row-blocks for perfect balance ----------------
// 256 blocks; block handles I = p and I = 15-p -> 68 K-steps each, uniform.
__global__ __launch_bounds__(512, 2) void pv_bal(const unsigned short* __restrict__ Sp,
                                                 const unsigned short* __restrict__ Vt,
                                                 float* __restrict__ out) {
  __shared__ unsigned short smA[2][16384];
  __shared__ unsigned short smB[2][8192];
  const int tid = threadIdx.x;
  const int bid = blockIdx.x;
  const int sw = (bid & 7) * 32 + (bid >> 3);   // 256 = 8*32, bijective
  const int p = sw >> 5, b = (sw >> 3) & 3, nt = sw & 7;
  const int lane = tid & 63, w = tid >> 6;
  const int wm = w >> 1, wn = w & 1;
  const int lr = lane & 15, hi = lane >> 4;
  f32x4 acc[4][4];
#pragma unroll
  for (int half = 0; half < 2; ++half) {
    const int I = half ? (15 - p) : p;
    {
      const f32x4 z4 = {0.f, 0.f, 0.f, 0.f};
#pragma unroll
      for (int f = 0; f < 4; ++f)
#pragma unroll
        for (int g = 0; g < 4; ++g) acc[f][g] = z4;
    }
    const char* A = (const char*)(Sp + (size_t)b * S_BATCH + (size_t)(I * (I + 1) / 2) * 65536);
    const size_t lda = (size_t)(I + 1) * 512;   // bytes
    const char* Bp = (const char*)Vt + ((size_t)b * D_SZ + (size_t)nt * 128) * (S_SZ * 2);
    mainloop128(A, lda, Bp, S_SZ * 2, (I + 1) * 4, smA, smB, tid, acc);
#pragma unroll
    for (int f = 0; f < 4; ++f)
#pragma unroll
      for (int g = 0; g < 4; ++g)
#pragma unroll
        for (int j = 0; j < 4; ++j) {
          const int m = wm * 64 + f * 16 + hi * 4 + j;
          const int n = nt * 128 + wn * 64 + g * 16 + lr;
          out[((size_t)b * S_SZ + (size_t)I * 256 + m) * D_SZ + n] = acc[f][g][j];
        }
    __syncthreads();
  }
}

extern "C" void kernel_launch(void* const* d_in, const int* in_sizes, int n_in,
                              void* d_out, int out_size, void* d_ws, size_t ws_size,
                              hipStream_t stream) {
  (void)in_sizes; (void)n_in; (void)out_size; (void)ws_size;
  const float* x  = (const float*)d_in[0];
  const float* Wq = (const float*)d_in[1];
  const float* Wk = (const float*)d_in[2];
  const float* Wv = (const float*)d_in[3];
  float* out = (float*)d_out;
  unsigned short* ws = (unsigned short*)d_ws;

  cast_x_kernel<<<8192, 256, 0, stream>>>(x, ws + OFF_XB);
  cast_wt_kernel<<<dim3(16, 16, 3), 256, 0, stream>>>(Wq, Wk, Wv, ws + OFF_WT);
  gemm_qkv256<<<768, 512, 0, stream>>>(ws + OFF_XB, ws + OFF_WT,
                                       ws + OFF_Q, ws + OFF_K, ws + OFF_V);
  transpose_v_kernel<<<dim3(64, 16, 4), 256, 0, stream>>>(ws + OFF_V, ws + OFF_VT);
  s_gemm256<<<544, 512, 0, stream>>>(ws + OFF_Q, ws + OFF_K, ws + OFF_S);
  softmax_kernel<<<4096, 256, 0, stream>>>(ws + OFF_S);
  pv_bal<<<256, 512, 0, stream>>>(ws + OFF_S, ws + OFF_VT, out);
}